// Round 5
// baseline (42.005 us; speedup 1.0000x reference)
//
#include <hip/hip_runtime.h>

#define WSZ    64
#define BLOCK  256
#define INV2PI 0.15915494309189535f   // v_sin/v_cos take revolutions

#define VM_WAIT4 asm volatile("s_waitcnt vmcnt(4)" ::: "memory")
#define VM_WAIT0 asm volatile("s_waitcnt vmcnt(0)" ::: "memory")

__device__ __forceinline__ float rl(float v, int t) {
    return __builtin_bit_cast(float, __builtin_amdgcn_readlane(__builtin_bit_cast(int, v), t));
}

__global__ __launch_bounds__(BLOCK) void sq_main(
    const float* __restrict__ x,
    const float* __restrict__ theta,
    const float* __restrict__ w,
    const float* __restrict__ bias,
    float* __restrict__ out)
{
    // Per wave: 2 quarter-buffers of 4KB (64 rows x 4 float4), double-buffered.
    // 4 waves x 8KB = 32KB/block -> 5 blocks/CU = 20 waves/CU. No cross-wave sync.
    __shared__ float4 xs4[4][2][256];

    const int tid  = threadIdx.x;
    const int lane = tid & 63;
    const int wid  = tid >> 6;
    const size_t wrow0 = (size_t)blockIdx.x * BLOCK + wid * 64;
    const float* xw = x + wrow0 * WSZ;

    float4* buf0 = &xs4[wid][0][0];
    float4* buf1 = &xs4[wid][1][0];

    // ---- coefs for step t = lane, held in 8 VGPRs (fetched later via readlane) ----
    // M = Rz(b)*Ry(a) as Bloch 3x3: [cb*ca, -sb, cb*sa; sb*ca, cb, sb*sa; -sa, 0, ca]
    float2 th = reinterpret_cast<const float2*>(theta)[lane];
    float sa = __builtin_amdgcn_sinf(th.x * INV2PI);
    float ca = __builtin_amdgcn_cosf(th.x * INV2PI);
    float sb = __builtin_amdgcn_sinf(th.y * INV2PI);
    float cb = __builtin_amdgcn_cosf(th.y * INV2PI);
    float m00 = cb * ca, m01 = -sb,     m02 = cb * sa;
    float m10 = sb * ca, m11 = cb,      m12 = sb * sa;
    float m20 = -sa,     m22 = ca;

    // ---- DMA a 16-col quarter q into buf (LDS linear, global source pre-swizzled).
    // LDS slot l = row*4 + c_lds holds global chunk c_g = c_lds ^ ((row>>1)&3).
    auto issue = [&](int q, float4* buf) {
        #pragma unroll
        for (int i = 0; i < 4; ++i) {
            int l    = i * 64 + lane;
            int row  = l >> 2;
            int cl   = l & 3;
            int cg   = cl ^ ((row >> 1) & 3);
            const float* src = xw + (size_t)row * WSZ + q * 16 + cg * 4;
            __builtin_amdgcn_global_load_lds(
                (const __attribute__((address_space(1))) void*)src,
                (__attribute__((address_space(3))) void*)&buf[i * 64], 16, 0, 0);
        }
    };

    // ---- 16 steps of Bloch evolution from one quarter-buffer ----
    float vx = 0.0f, vy = 0.0f, vz = 1.0f;
    const int key = (lane >> 1) & 3;

    auto quarter = [&](int q, const float4* buf) {
        #pragma unroll
        for (int c = 0; c < 4; ++c) {
            float4 xv = buf[lane * 4 + (c ^ key)];   // ~conflict-free ds_read_b128
            float xr[4] = {xv.x, xv.y, xv.z, xv.w};
            #pragma unroll
            for (int j = 0; j < 4; ++j) {
                const int t = q * 16 + c * 4 + j;    // compile-time step index
                float r  = xr[j] * INV2PI;
                float s  = __builtin_amdgcn_sinf(r);
                float co = __builtin_amdgcn_cosf(r);
                float y1 = co * vy - s * vz;         // Rx(x_t)
                float z1 = s  * vy + co * vz;
                float nx = rl(m00,t) * vx + rl(m01,t) * y1 + rl(m02,t) * z1;
                float ny = rl(m10,t) * vx + rl(m11,t) * y1 + rl(m12,t) * z1;
                float nz = rl(m20,t) * vx + rl(m22,t) * z1;   // m21 == 0
                vx = nx; vy = ny; vz = nz;
            }
        }
    };

    // ---- pipeline: issue q0,q1; compute q0 | issue q2; compute q1 | issue q3; ...
    issue(0, buf0);
    issue(1, buf1);
    VM_WAIT4;                // q0 landed (q1's 4 still in flight)
    quarter(0, buf0);
    issue(2, buf0);
    VM_WAIT4;                // q1 landed (q2 in flight)
    quarter(1, buf1);
    issue(3, buf1);
    VM_WAIT4;                // q2 landed (q3 in flight)
    quarter(2, buf0);
    VM_WAIT0;                // q3 landed
    quarter(3, buf1);

    out[wrow0 + lane] = vz * w[0] + bias[0];
}

extern "C" void kernel_launch(void* const* d_in, const int* in_sizes, int n_in,
                              void* d_out, int out_size, void* d_ws, size_t ws_size,
                              hipStream_t stream) {
    const float* x     = (const float*)d_in[0];
    const float* theta = (const float*)d_in[1];
    const float* w     = (const float*)d_in[2];
    const float* b     = (const float*)d_in[3];
    float* out = (float*)d_out;

    int nrows = out_size;                 // B = 524288 (divisible by 256)
    int grid  = nrows / BLOCK;            // 2048 blocks
    sq_main<<<grid, BLOCK, 0, stream>>>(x, theta, w, b, out);
}